// Round 11
// baseline (516.053 us; speedup 1.0000x reference)
//
#include <hip/hip_runtime.h>

#define N_NODES 100000
#define N_EDGES 1600000
#define F_IN 64
#define HIDDEN 128
#define N_GRAPHS 1024
#define EPS 1e-5f

typedef short short8 __attribute__((ext_vector_type(8)));
typedef float f32x4 __attribute__((ext_vector_type(4)));
typedef unsigned int uint;
typedef unsigned short ushort;

// fp32 -> bf16 round-to-nearest-even (finite values only)
__device__ __forceinline__ ushort f2b(float f) {
    uint x = __float_as_uint(f);
    return (ushort)((x + 0x7fffu + ((x >> 16) & 1u)) >> 16);
}
__device__ __forceinline__ uint pack2(float a, float b) {
    return (uint)f2b(a) | ((uint)f2b(b) << 16);
}
__device__ __forceinline__ float b2f_lo(uint u) { return __uint_as_float(u << 16); }
__device__ __forceinline__ float b2f_hi(uint u) { return __uint_as_float(u & 0xffff0000u); }

// two-level counting sort parameters
#define NBLK_A 128
#define CHUNK ((N_EDGES + NBLK_A - 1) / NBLK_A)        // 12500
#define BUCK_SHIFT 9                                    // 512-node windows
#define NBUCK ((N_NODES + 511) / 512)                   // 196
#define SCAN_M (NBUCK * NBLK_A)                         // 25088
#define SCAN_T ((SCAN_M + 1023) / 1024)                 // 25 tiles

// ---------------------------------------------------------------------------
// Fused prep (x->bf16, W->bf16 [c][k], pooled zero) + bin_count.
// ---------------------------------------------------------------------------

#define PREP_X   (N_NODES * 32)       // uints of xb
#define PREP_W0  8192                 // uints of wb0 (128*128/2)
#define PREP_W1  16384                // uints of wb1 (128*256/2)
#define PREP_W2  16384
#define PREP_PZ  (N_GRAPHS * HIDDEN)  // floats of pooled
#define PREP_TOT (PREP_X + PREP_W0 + PREP_W1 + PREP_W2 + PREP_PZ)

__device__ __forceinline__ void cvt_w_elem(const float* W0, const float* W1, int F,
                                           int idx, uint* out) {
    int K = 2 * F;
    int c  = idx / (K / 2);
    int k2 = (idx % (K / 2)) * 2;
    float f0 = (k2 < F) ? W0[k2 * 128 + c] : W1[(k2 - F) * 128 + c];
    float f1 = (k2 + 1 < F) ? W0[(k2 + 1) * 128 + c] : W1[(k2 + 1 - F) * 128 + c];
    out[idx] = pack2(f0, f1);
}

__global__ __launch_bounds__(256) void prep_count_kernel(
        const float* __restrict__ x, uint* __restrict__ xb,
        const float* __restrict__ rw0, const float* __restrict__ ow0,
        const float* __restrict__ rw1, const float* __restrict__ ow1,
        const float* __restrict__ rw2, const float* __restrict__ ow2,
        uint* __restrict__ wb0, uint* __restrict__ wb1,
        uint* __restrict__ wb2, float* __restrict__ pooled,
        const int* __restrict__ ei, int* __restrict__ counts) {
    __shared__ int cnt[NBUCK];
    int t = threadIdx.x;
    if (blockIdx.x < NBLK_A) {
        int blk = blockIdx.x;
        for (int i = t; i < NBUCK; i += 256) cnt[i] = 0;
        __syncthreads();
        int e0 = blk * CHUNK, e1 = min(e0 + CHUNK, N_EDGES);
        for (int e = e0 + t; e < e1; e += 256)
            atomicAdd(&cnt[ei[N_EDGES + e] >> BUCK_SHIFT], 1);
        __syncthreads();
        for (int i = t; i < NBUCK; i += 256) counts[i * NBLK_A + blk] = cnt[i];
        return;
    }
    int i = (blockIdx.x - NBLK_A) * 256 + t;
    if (i < PREP_X) {
        float2 v = ((const float2*)x)[i];
        xb[i] = pack2(v.x, v.y);
        return;
    }
    i -= PREP_X;
    if (i < PREP_W0) { cvt_w_elem(rw0, ow0, 64, i, wb0); return; }
    i -= PREP_W0;
    if (i < PREP_W1) { cvt_w_elem(rw1, ow1, 128, i, wb1); return; }
    i -= PREP_W1;
    if (i < PREP_W2) { cvt_w_elem(rw2, ow2, 128, i, wb2); return; }
    i -= PREP_W2;
    if (i < PREP_PZ) pooled[i] = 0.f;
}

// ---------------------------------------------------------------------------
// Hierarchical exclusive scan of counts[SCAN_M]
// ---------------------------------------------------------------------------

__global__ __launch_bounds__(1024) void sc_reduce_kernel(const int* __restrict__ counts,
                                                         int* __restrict__ partial) {
    __shared__ int lds[16];
    int b = blockIdx.x, t = threadIdx.x;
    int i = b * 1024 + t;
    int v = (i < SCAN_M) ? counts[i] : 0;
    #pragma unroll
    for (int off = 32; off > 0; off >>= 1) v += __shfl_down(v, off);
    if ((t & 63) == 0) lds[t >> 6] = v;
    __syncthreads();
    if (t == 0) {
        int s = 0;
        #pragma unroll
        for (int j = 0; j < 16; ++j) s += lds[j];
        partial[b] = s;
    }
}

__global__ __launch_bounds__(1024) void sc_apply_kernel(int* __restrict__ counts,
                                                        const int* __restrict__ partial,
                                                        int* __restrict__ rowptr) {
    __shared__ int lds[1024];
    __shared__ int base;
    int b = blockIdx.x, t = threadIdx.x;
    if (t == 0) {
        int s = 0;
        for (int j = 0; j < b; ++j) s += partial[j];
        base = s;
        if (b == 0) rowptr[N_NODES] = N_EDGES;
    }
    int i = b * 1024 + t;
    int v = (i < SCAN_M) ? counts[i] : 0;
    lds[t] = v;
    __syncthreads();
    for (int off = 1; off < 1024; off <<= 1) {
        int x = (t >= off) ? lds[t - off] : 0;
        __syncthreads();
        lds[t] += x;
        __syncthreads();
    }
    if (i < SCAN_M) counts[i] = lds[t] - v + base;
}

// scatter edges into coarse-bucket order; payload packed to one int2:
//   x = src, y = (bf16(w) << 16) | (dst & 511)
__global__ __launch_bounds__(256) void bin_scatter_kernel(const int* __restrict__ ei,
                                                          const float* __restrict__ ea,
                                                          const int* __restrict__ counts,
                                                          int2* __restrict__ emb) {
    __shared__ int cur[NBUCK];
    int blk = blockIdx.x, t = threadIdx.x;
    for (int i = t; i < NBUCK; i += 256) cur[i] = counts[i * NBLK_A + blk];
    __syncthreads();
    int e0 = blk * CHUNK, e1 = min(e0 + CHUNK, N_EDGES);
    for (int e = e0 + t; e < e1; e += 256) {
        int s = ei[e], d = ei[N_EDGES + e];
        uint y = ((uint)f2b(ea[e]) << 16) | (uint)(d & 511);
        int p = atomicAdd(&cur[d >> BUCK_SHIFT], 1);
        emb[p] = make_int2(s, (int)y);
    }
}

// per-bucket exact sort + rowptr; final em: x = src, y = float bits of bf16 w
__global__ __launch_bounds__(1024) void bucket_build_kernel(const int* __restrict__ counts,
                                                            const int2* __restrict__ emb,
                                                            int* __restrict__ rowptr,
                                                            int2* __restrict__ em) {
    __shared__ int hist[512];
    __shared__ int cursor[512];
    int b = blockIdx.x, t = threadIdx.x;
    int beg = counts[b * NBLK_A];
    int end = (b + 1 < NBUCK) ? counts[(b + 1) * NBLK_A] : N_EDGES;
    int nbase = b << BUCK_SHIFT;
    int nnodes = min(512, N_NODES - nbase);

    if (t < 512) hist[t] = 0;
    __syncthreads();
    for (int e = beg + t; e < end; e += 1024)
        atomicAdd(&hist[(uint)emb[e].y & 511u], 1);
    __syncthreads();

    int v = (t < 512) ? hist[t] : 0;
    for (int off = 1; off < 512; off <<= 1) {
        int x = (t < 512 && t >= off) ? hist[t - off] : 0;
        __syncthreads();
        if (t < 512) hist[t] += x;
        __syncthreads();
    }
    if (t < 512) {
        int excl = hist[t] - v;
        cursor[t] = beg + excl;
        if (t < nnodes) rowptr[nbase + t] = beg + excl;
    }
    __syncthreads();

    for (int e = beg + t; e < end; e += 1024) {
        int2 m = emb[e];
        int p = atomicAdd(&cursor[(uint)m.y & 511u], 1);
        em[p] = make_int2(m.x, (int)((uint)m.y & 0xffff0000u));
    }
}

// ---------------------------------------------------------------------------
// Aggregation: one wave per node, 4 x 16-lane groups; group g handles edge
// e+g, slot covers 16B (F=128) / 8B (F=64) of the row. 2-deep unroll.
// ---------------------------------------------------------------------------

template <int F>
__global__ __launch_bounds__(256) void agg_kernel(const ushort* __restrict__ h,
                                                  const int* __restrict__ rowptr,
                                                  const int2* __restrict__ em,
                                                  ushort* __restrict__ agg) {
    int node = blockIdx.x * 4 + (threadIdx.x >> 6);
    int lane = threadIdx.x & 63;
    int g  = lane >> 4;
    int sl = lane & 15;
    int beg = rowptr[node], end = rowptr[node + 1];
    int e = beg;

    if (F == 128) {
        float acc[8] = {};
        for (; e + 8 <= end; e += 8) {
            int2 mA = em[e + g];
            int2 mB = em[e + 4 + g];
            uint4 vA = *(const uint4*)(h + (size_t)mA.x * 128 + sl * 8);
            uint4 vB = *(const uint4*)(h + (size_t)mB.x * 128 + sl * 8);
            float wA = __int_as_float(mA.y), wB = __int_as_float(mB.y);
            acc[0] = fmaf(b2f_lo(vA.x), wA, acc[0]);
            acc[1] = fmaf(b2f_hi(vA.x), wA, acc[1]);
            acc[2] = fmaf(b2f_lo(vA.y), wA, acc[2]);
            acc[3] = fmaf(b2f_hi(vA.y), wA, acc[3]);
            acc[4] = fmaf(b2f_lo(vA.z), wA, acc[4]);
            acc[5] = fmaf(b2f_hi(vA.z), wA, acc[5]);
            acc[6] = fmaf(b2f_lo(vA.w), wA, acc[6]);
            acc[7] = fmaf(b2f_hi(vA.w), wA, acc[7]);
            acc[0] = fmaf(b2f_lo(vB.x), wB, acc[0]);
            acc[1] = fmaf(b2f_hi(vB.x), wB, acc[1]);
            acc[2] = fmaf(b2f_lo(vB.y), wB, acc[2]);
            acc[3] = fmaf(b2f_hi(vB.y), wB, acc[3]);
            acc[4] = fmaf(b2f_lo(vB.z), wB, acc[4]);
            acc[5] = fmaf(b2f_hi(vB.z), wB, acc[5]);
            acc[6] = fmaf(b2f_lo(vB.w), wB, acc[6]);
            acc[7] = fmaf(b2f_hi(vB.w), wB, acc[7]);
        }
        for (; e < end; e += 4) {
            int ej = e + g;
            if (ej < end) {
                int2 m = em[ej];
                uint4 v = *(const uint4*)(h + (size_t)m.x * 128 + sl * 8);
                float w = __int_as_float(m.y);
                acc[0] = fmaf(b2f_lo(v.x), w, acc[0]);
                acc[1] = fmaf(b2f_hi(v.x), w, acc[1]);
                acc[2] = fmaf(b2f_lo(v.y), w, acc[2]);
                acc[3] = fmaf(b2f_hi(v.y), w, acc[3]);
                acc[4] = fmaf(b2f_lo(v.z), w, acc[4]);
                acc[5] = fmaf(b2f_hi(v.z), w, acc[5]);
                acc[6] = fmaf(b2f_lo(v.w), w, acc[6]);
                acc[7] = fmaf(b2f_hi(v.w), w, acc[7]);
            }
        }
        #pragma unroll
        for (int f = 0; f < 8; ++f) {
            acc[f] += __shfl_xor(acc[f], 16);
            acc[f] += __shfl_xor(acc[f], 32);
        }
        if (lane < 16) {
            uint4 o;
            o.x = pack2(acc[0], acc[1]);
            o.y = pack2(acc[2], acc[3]);
            o.z = pack2(acc[4], acc[5]);
            o.w = pack2(acc[6], acc[7]);
            *(uint4*)(agg + (size_t)node * 128 + sl * 8) = o;
        }
    } else {
        float acc[4] = {};
        for (; e + 8 <= end; e += 8) {
            int2 mA = em[e + g];
            int2 mB = em[e + 4 + g];
            uint2 vA = *(const uint2*)(h + (size_t)mA.x * 64 + sl * 4);
            uint2 vB = *(const uint2*)(h + (size_t)mB.x * 64 + sl * 4);
            float wA = __int_as_float(mA.y), wB = __int_as_float(mB.y);
            acc[0] = fmaf(b2f_lo(vA.x), wA, acc[0]);
            acc[1] = fmaf(b2f_hi(vA.x), wA, acc[1]);
            acc[2] = fmaf(b2f_lo(vA.y), wA, acc[2]);
            acc[3] = fmaf(b2f_hi(vA.y), wA, acc[3]);
            acc[0] = fmaf(b2f_lo(vB.x), wB, acc[0]);
            acc[1] = fmaf(b2f_hi(vB.x), wB, acc[1]);
            acc[2] = fmaf(b2f_lo(vB.y), wB, acc[2]);
            acc[3] = fmaf(b2f_hi(vB.y), wB, acc[3]);
        }
        for (; e < end; e += 4) {
            int ej = e + g;
            if (ej < end) {
                int2 m = em[ej];
                uint2 v = *(const uint2*)(h + (size_t)m.x * 64 + sl * 4);
                float w = __int_as_float(m.y);
                acc[0] = fmaf(b2f_lo(v.x), w, acc[0]);
                acc[1] = fmaf(b2f_hi(v.x), w, acc[1]);
                acc[2] = fmaf(b2f_lo(v.y), w, acc[2]);
                acc[3] = fmaf(b2f_hi(v.y), w, acc[3]);
            }
        }
        #pragma unroll
        for (int f = 0; f < 4; ++f) {
            acc[f] += __shfl_xor(acc[f], 16);
            acc[f] += __shfl_xor(acc[f], 32);
        }
        if (lane < 16) {
            uint2 o;
            o.x = pack2(acc[0], acc[1]);
            o.y = pack2(acc[2], acc[3]);
            *(uint2*)(agg + (size_t)node * 64 + sl * 4) = o;
        }
    }
}

// ---------------------------------------------------------------------------
// MFMA GEMM + bias + BN + ReLU. bf16 in, fp32 accum. K = 2F.
// R9 structure (best measured): K-split W half-panel in LDS, 4 blocks/CU,
// A streamed with 1-deep register prefetch inside each half.
// POOL=true (last layer): instead of storing h, accumulate relu outputs into
// an 8-graph x 128 LDS slab (batch sorted => a 128-row block spans <=~4
// graphs; guarded fallback to direct global atomics), flush <=1024 global
// atomics per block. Skips the 25.6 MB h write + pool kernel entirely.
// ---------------------------------------------------------------------------

template <int F, bool POOL>
__global__ __launch_bounds__(256, 4) void gemm_mfma(const ushort* __restrict__ A0,
                                                    const ushort* __restrict__ A1,
                                                    const ushort* __restrict__ Wb,
                                                    const float* __restrict__ bias,
                                                    const float* __restrict__ bng,
                                                    const float* __restrict__ bnb,
                                                    const float* __restrict__ bnm,
                                                    const float* __restrict__ bnv,
                                                    ushort* __restrict__ out,
                                                    const int* __restrict__ batch,
                                                    float* __restrict__ pooled) {
    constexpr int K = 2 * F;
    constexpr int LDW = F + 8;
    __shared__ ushort Wl[128 * LDW];
    __shared__ float pslot[POOL ? 1024 : 1];   // 8 graphs x 128 feats
    __shared__ int   sbatch[POOL ? 128 : 1];
    __shared__ int   srange[2];

    int t = threadIdx.x;
    int rbBlock = blockIdx.x * 128;

    if (POOL) {
        for (int i = t; i < 1024; i += 256) pslot[i] = 0.f;
        if (t < 128) {
            int r = rbBlock + t;
            sbatch[t] = (r < N_NODES) ? batch[r] : -1;
        }
        if (t == 0) {
            srange[0] = batch[rbBlock];
            srange[1] = batch[min(rbBlock + 127, N_NODES - 1)];
        }
    }

    int wave = t >> 6, lane = t & 63;
    int m = lane & 15, quad = lane >> 4;
    int r0 = rbBlock + wave * 32 + m;
    int r1 = r0 + 16;

    f32x4 acc0[8], acc1[8];
    #pragma unroll
    for (int i = 0; i < 8; ++i) { acc0[i] = (f32x4)(0.f); acc1[i] = (f32x4)(0.f); }

    #pragma unroll
    for (int half = 0; half < 2; ++half) {
        const ushort* A = half ? A1 : A0;
        for (int idx = t; idx < 128 * (F / 8); idx += 256) {
            int c  = idx / (F / 8);
            int k8 = (idx % (F / 8)) * 8;
            *(short8*)&Wl[c * LDW + k8] = *(const short8*)&Wb[c * K + half * F + k8];
        }
        __syncthreads();

        auto loadA = [&](int row, int k0) -> short8 {
            short8 v = {};
            if (row < N_NODES) v = *(const short8*)(A + (size_t)row * F + k0);
            return v;
        };

        short8 a0 = loadA(r0, quad * 8);
        short8 a1 = loadA(r1, quad * 8);
        for (int kc = 0; kc < F; kc += 32) {
            int k0 = kc + quad * 8;
            short8 na0 = {}, na1 = {};
            if (kc + 32 < F) {
                na0 = loadA(r0, k0 + 32);
                na1 = loadA(r1, k0 + 32);
            }
            #pragma unroll
            for (int ct = 0; ct < 8; ++ct) {
                short8 b = *(const short8*)&Wl[(ct * 16 + m) * LDW + k0];
                acc0[ct] = __builtin_amdgcn_mfma_f32_16x16x32_bf16(a0, b, acc0[ct], 0, 0, 0);
                acc1[ct] = __builtin_amdgcn_mfma_f32_16x16x32_bf16(a1, b, acc1[ct], 0, 0, 0);
            }
            a0 = na0; a1 = na1;
        }
        __syncthreads();
    }

    int gmin = 0;
    bool fast = true;
    if (POOL) {
        gmin = srange[0];
        fast = (srange[1] - gmin) < 8;
    }

    int rb0 = rbBlock + wave * 32 + quad * 4;
    #pragma unroll
    for (int ct = 0; ct < 8; ++ct) {
        int c = ct * 16 + m;
        float sc = bng[c] * rsqrtf(bnv[c] + EPS);
        float sh = bnb[c] - bnm[c] * sc;
        float bi = bias[c];
        #pragma unroll
        for (int reg = 0; reg < 4; ++reg) {
            int r = rb0 + reg;
            if (r < N_NODES) {
                float v = fmaxf(fmaf(acc0[ct][reg] + bi, sc, sh), 0.f);
                if (POOL) {
                    if (fast) atomicAdd(&pslot[(sbatch[r - rbBlock] - gmin) * 128 + c], v);
                    else      atomicAdd(&pooled[(size_t)sbatch[r - rbBlock] * 128 + c], v);
                } else {
                    out[(size_t)r * 128 + c] = f2b(v);
                }
            }
            int r2 = rb0 + 16 + reg;
            if (r2 < N_NODES) {
                float v = fmaxf(fmaf(acc1[ct][reg] + bi, sc, sh), 0.f);
                if (POOL) {
                    if (fast) atomicAdd(&pslot[(sbatch[r2 - rbBlock] - gmin) * 128 + c], v);
                    else      atomicAdd(&pooled[(size_t)sbatch[r2 - rbBlock] * 128 + c], v);
                } else {
                    out[(size_t)r2 * 128 + c] = f2b(v);
                }
            }
        }
    }

    if (POOL) {
        __syncthreads();
        if (fast) {
            for (int i = t; i < 1024; i += 256) {
                float v = pslot[i];
                int g = gmin + (i >> 7);
                if (v != 0.f && g < N_GRAPHS)
                    atomicAdd(&pooled[(size_t)g * 128 + (i & 127)], v);
            }
        }
    }
}

// ---------------------------------------------------------------------------
// Head: counts via binary search on sorted batch, one wave per graph
// ---------------------------------------------------------------------------

__global__ __launch_bounds__(64) void head_kernel(const float* __restrict__ pooled,
                                                  const int* __restrict__ batch,
                                                  const float* __restrict__ w1,
                                                  const float* __restrict__ b1,
                                                  const float* __restrict__ w2,
                                                  const float* __restrict__ b2,
                                                  float* __restrict__ out) {
    int g = blockIdx.x;
    int j = threadIdx.x;
    int lo = 0, hi = N_NODES;
    while (lo < hi) { int m = (lo + hi) >> 1; if (batch[m] <  g) lo = m + 1; else hi = m; }
    int start = lo;
    lo = 0; hi = N_NODES;
    while (lo < hi) { int m = (lo + hi) >> 1; if (batch[m] <= g) lo = m + 1; else hi = m; }
    float inv = 1.0f / fmaxf((float)(lo - start), 1.0f);

    float acc = b1[j];
    #pragma unroll 4
    for (int k = 0; k < 128; ++k)
        acc = fmaf(pooled[(size_t)g * 128 + k] * inv, w1[k * 64 + j], acc);
    float prod = fmaxf(acc, 0.f) * w2[j];
    #pragma unroll
    for (int off = 32; off > 0; off >>= 1)
        prod += __shfl_down(prod, off);
    if (j == 0) out[g] = prod + b2[0];
}

// ---------------------------------------------------------------------------

extern "C" void kernel_launch(void* const* d_in, const int* in_sizes, int n_in,
                              void* d_out, int out_size, void* d_ws, size_t ws_size,
                              hipStream_t stream) {
    const float* x     = (const float*)d_in[0];
    const int*   ei    = (const int*)d_in[1];
    const float* ea    = (const float*)d_in[2];
    const int*   batch = (const int*)d_in[3];
    const float* rel_w[3]  = {(const float*)d_in[4],  (const float*)d_in[11], (const float*)d_in[18]};
    const float* rel_b[3]  = {(const float*)d_in[5],  (const float*)d_in[12], (const float*)d_in[19]};
    const float* root_w[3] = {(const float*)d_in[6],  (const float*)d_in[13], (const float*)d_in[20]};
    const float* bn_g[3]   = {(const float*)d_in[7],  (const float*)d_in[14], (const float*)d_in[21]};
    const float* bn_b[3]   = {(const float*)d_in[8],  (const float*)d_in[15], (const float*)d_in[22]};
    const float* bn_m[3]   = {(const float*)d_in[9],  (const float*)d_in[16], (const float*)d_in[23]};
    const float* bn_v[3]   = {(const float*)d_in[10], (const float*)d_in[17], (const float*)d_in[24]};
    const float* head_w1 = (const float*)d_in[25];
    const float* head_b1 = (const float*)d_in[26];
    const float* head_w2 = (const float*)d_in[27];
    const float* head_b2 = (const float*)d_in[28];
    float* out = (float*)d_out;

    // workspace layout (~104 MB)
    char* ws = (char*)d_ws;
    int*    rowptr  = (int*)(ws + 0);             // N_NODES+1 ints
    int*    counts  = (int*)(ws + 401408);        // SCAN_M ints
    int*    partial = (int*)(ws + 503808);        // SCAN_T ints
    int2*   em      = (int2*)(ws + 524288);       // E int2 (src, bf16 w bits)
    ushort* xb      = (ushort*)(ws + 13631488);   // N*64 bf16
    ushort* h_a     = (ushort*)(ws + 26431488);   // N*128 bf16
    ushort* h_b     = (ushort*)(ws + 52031488);   // N*128 bf16
    ushort* aggb    = (ushort*)(ws + 77631488);   // N*128 bf16 (layer0 uses N*64)
    float*  pooled  = (float*)(ws + 103231488);   // 1024*128 fp32
    ushort* wb      = (ushort*)(ws + 103755776);  // 81920 bf16 (3 W panels)
    // sort scratch aliases aggb region (dead until first agg)
    int2*   emb = (int2*)(ws + 77631488);         // E int2 packed

    ushort* wb0 = wb;            // 128*128
    ushort* wb1 = wb + 16384;    // 128*256
    ushort* wb2 = wb + 49152;    // 128*256

    const int PREP_BLOCKS = NBLK_A + (PREP_TOT + 255) / 256;
    prep_count_kernel<<<PREP_BLOCKS, 256, 0, stream>>>(
        x, (uint*)xb, rel_w[0], root_w[0], rel_w[1], root_w[1], rel_w[2], root_w[2],
        (uint*)wb0, (uint*)wb1, (uint*)wb2, pooled, ei, counts);

    sc_reduce_kernel<<<SCAN_T, 1024, 0, stream>>>(counts, partial);
    sc_apply_kernel<<<SCAN_T, 1024, 0, stream>>>(counts, partial, rowptr);
    bin_scatter_kernel<<<NBLK_A, 256, 0, stream>>>(ei, ea, counts, emb);
    bucket_build_kernel<<<NBUCK, 1024, 0, stream>>>(counts, emb, rowptr, em);

    const int AGG_BLOCKS  = N_NODES / 4;
    const int GEMM_BLOCKS = (N_NODES + 127) / 128;

    agg_kernel<64><<<AGG_BLOCKS, 256, 0, stream>>>(xb, rowptr, em, aggb);
    gemm_mfma<64, false><<<GEMM_BLOCKS, 256, 0, stream>>>(aggb, xb, wb0, rel_b[0],
                                                          bn_g[0], bn_b[0], bn_m[0], bn_v[0],
                                                          h_a, batch, pooled);
    agg_kernel<128><<<AGG_BLOCKS, 256, 0, stream>>>(h_a, rowptr, em, aggb);
    gemm_mfma<128, false><<<GEMM_BLOCKS, 256, 0, stream>>>(aggb, h_a, wb1, rel_b[1],
                                                           bn_g[1], bn_b[1], bn_m[1], bn_v[1],
                                                           h_b, batch, pooled);
    agg_kernel<128><<<AGG_BLOCKS, 256, 0, stream>>>(h_b, rowptr, em, aggb);
    gemm_mfma<128, true><<<GEMM_BLOCKS, 256, 0, stream>>>(aggb, h_b, wb2, rel_b[2],
                                                          bn_g[2], bn_b[2], bn_m[2], bn_v[2],
                                                          h_a, batch, pooled);

    head_kernel<<<N_GRAPHS, 64, 0, stream>>>(pooled, batch, head_w1, head_b1, head_w2, head_b2, out);
}

// Round 12
// 459.913 us; speedup vs baseline: 1.1221x; 1.1221x over previous
//
#include <hip/hip_runtime.h>

#define N_NODES 100000
#define N_EDGES 1600000
#define F_IN 64
#define HIDDEN 128
#define N_GRAPHS 1024
#define EPS 1e-5f

typedef short short8 __attribute__((ext_vector_type(8)));
typedef float f32x4 __attribute__((ext_vector_type(4)));
typedef unsigned int uint;
typedef unsigned short ushort;

// fp32 -> bf16 round-to-nearest-even (finite values only)
__device__ __forceinline__ ushort f2b(float f) {
    uint x = __float_as_uint(f);
    return (ushort)((x + 0x7fffu + ((x >> 16) & 1u)) >> 16);
}
__device__ __forceinline__ uint pack2(float a, float b) {
    return (uint)f2b(a) | ((uint)f2b(b) << 16);
}
__device__ __forceinline__ float b2f_lo(uint u) { return __uint_as_float(u << 16); }
__device__ __forceinline__ float b2f_hi(uint u) { return __uint_as_float(u & 0xffff0000u); }

// two-level counting sort parameters
#define NBLK_A 128
#define CHUNK ((N_EDGES + NBLK_A - 1) / NBLK_A)        // 12500
#define BUCK_SHIFT 9                                    // 512-node windows
#define NBUCK ((N_NODES + 511) / 512)                   // 196
#define SCAN_M (NBUCK * NBLK_A)                         // 25088
#define SCAN_T ((SCAN_M + 1023) / 1024)                 // 25 tiles

// ---------------------------------------------------------------------------
// Fused prep (x->bf16, W->bf16 [c][k], pooled zero) + bin_count.
// ---------------------------------------------------------------------------

#define PREP_X   (N_NODES * 32)       // uints of xb
#define PREP_W0  8192                 // uints of wb0 (128*128/2)
#define PREP_W1  16384                // uints of wb1 (128*256/2)
#define PREP_W2  16384
#define PREP_PZ  (N_GRAPHS * HIDDEN)  // floats of pooled
#define PREP_TOT (PREP_X + PREP_W0 + PREP_W1 + PREP_W2 + PREP_PZ)

__device__ __forceinline__ void cvt_w_elem(const float* W0, const float* W1, int F,
                                           int idx, uint* out) {
    int K = 2 * F;
    int c  = idx / (K / 2);
    int k2 = (idx % (K / 2)) * 2;
    float f0 = (k2 < F) ? W0[k2 * 128 + c] : W1[(k2 - F) * 128 + c];
    float f1 = (k2 + 1 < F) ? W0[(k2 + 1) * 128 + c] : W1[(k2 + 1 - F) * 128 + c];
    out[idx] = pack2(f0, f1);
}

__global__ __launch_bounds__(256) void prep_count_kernel(
        const float* __restrict__ x, uint* __restrict__ xb,
        const float* __restrict__ rw0, const float* __restrict__ ow0,
        const float* __restrict__ rw1, const float* __restrict__ ow1,
        const float* __restrict__ rw2, const float* __restrict__ ow2,
        uint* __restrict__ wb0, uint* __restrict__ wb1,
        uint* __restrict__ wb2, float* __restrict__ pooled,
        const int* __restrict__ ei, int* __restrict__ counts) {
    __shared__ int cnt[NBUCK];
    int t = threadIdx.x;
    if (blockIdx.x < NBLK_A) {
        int blk = blockIdx.x;
        for (int i = t; i < NBUCK; i += 256) cnt[i] = 0;
        __syncthreads();
        int e0 = blk * CHUNK, e1 = min(e0 + CHUNK, N_EDGES);
        for (int e = e0 + t; e < e1; e += 256)
            atomicAdd(&cnt[ei[N_EDGES + e] >> BUCK_SHIFT], 1);
        __syncthreads();
        for (int i = t; i < NBUCK; i += 256) counts[i * NBLK_A + blk] = cnt[i];
        return;
    }
    int i = (blockIdx.x - NBLK_A) * 256 + t;
    if (i < PREP_X) {
        float2 v = ((const float2*)x)[i];
        xb[i] = pack2(v.x, v.y);
        return;
    }
    i -= PREP_X;
    if (i < PREP_W0) { cvt_w_elem(rw0, ow0, 64, i, wb0); return; }
    i -= PREP_W0;
    if (i < PREP_W1) { cvt_w_elem(rw1, ow1, 128, i, wb1); return; }
    i -= PREP_W1;
    if (i < PREP_W2) { cvt_w_elem(rw2, ow2, 128, i, wb2); return; }
    i -= PREP_W2;
    if (i < PREP_PZ) pooled[i] = 0.f;
}

// ---------------------------------------------------------------------------
// Hierarchical exclusive scan of counts[SCAN_M]
// ---------------------------------------------------------------------------

__global__ __launch_bounds__(1024) void sc_reduce_kernel(const int* __restrict__ counts,
                                                         int* __restrict__ partial) {
    __shared__ int lds[16];
    int b = blockIdx.x, t = threadIdx.x;
    int i = b * 1024 + t;
    int v = (i < SCAN_M) ? counts[i] : 0;
    #pragma unroll
    for (int off = 32; off > 0; off >>= 1) v += __shfl_down(v, off);
    if ((t & 63) == 0) lds[t >> 6] = v;
    __syncthreads();
    if (t == 0) {
        int s = 0;
        #pragma unroll
        for (int j = 0; j < 16; ++j) s += lds[j];
        partial[b] = s;
    }
}

// apply: block offset via parallel wave-load of partials + shfl reduce
__global__ __launch_bounds__(1024) void sc_apply_kernel(int* __restrict__ counts,
                                                        const int* __restrict__ partial,
                                                        int* __restrict__ rowptr) {
    __shared__ int lds[1024];
    __shared__ int sbase;
    int b = blockIdx.x, t = threadIdx.x;
    if (t < 64) {
        int v = (t < b) ? partial[t] : 0;   // SCAN_T = 25 <= 64 lanes
        #pragma unroll
        for (int off = 32; off > 0; off >>= 1) v += __shfl_down(v, off);
        if (t == 0) {
            sbase = v;
            if (b == 0) rowptr[N_NODES] = N_EDGES;
        }
    }
    int i = b * 1024 + t;
    int v = (i < SCAN_M) ? counts[i] : 0;
    lds[t] = v;
    __syncthreads();
    for (int off = 1; off < 1024; off <<= 1) {
        int x = (t >= off) ? lds[t - off] : 0;
        __syncthreads();
        lds[t] += x;
        __syncthreads();
    }
    if (i < SCAN_M) counts[i] = lds[t] - v + sbase;
}

// scatter edges into coarse-bucket order; payload packed to one int2:
//   x = src, y = (bf16(w) << 16) | (dst & 511)
__global__ __launch_bounds__(256) void bin_scatter_kernel(const int* __restrict__ ei,
                                                          const float* __restrict__ ea,
                                                          const int* __restrict__ counts,
                                                          int2* __restrict__ emb) {
    __shared__ int cur[NBUCK];
    int blk = blockIdx.x, t = threadIdx.x;
    for (int i = t; i < NBUCK; i += 256) cur[i] = counts[i * NBLK_A + blk];
    __syncthreads();
    int e0 = blk * CHUNK, e1 = min(e0 + CHUNK, N_EDGES);
    for (int e = e0 + t; e < e1; e += 256) {
        int s = ei[e], d = ei[N_EDGES + e];
        uint y = ((uint)f2b(ea[e]) << 16) | (uint)(d & 511);
        int p = atomicAdd(&cur[d >> BUCK_SHIFT], 1);
        emb[p] = make_int2(s, (int)y);
    }
}

// per-bucket exact sort + rowptr; final em: x = src, y = float bits of bf16 w
__global__ __launch_bounds__(1024) void bucket_build_kernel(const int* __restrict__ counts,
                                                            const int2* __restrict__ emb,
                                                            int* __restrict__ rowptr,
                                                            int2* __restrict__ em) {
    __shared__ int hist[512];
    __shared__ int cursor[512];
    int b = blockIdx.x, t = threadIdx.x;
    int beg = counts[b * NBLK_A];
    int end = (b + 1 < NBUCK) ? counts[(b + 1) * NBLK_A] : N_EDGES;
    int nbase = b << BUCK_SHIFT;
    int nnodes = min(512, N_NODES - nbase);

    if (t < 512) hist[t] = 0;
    __syncthreads();
    for (int e = beg + t; e < end; e += 1024)
        atomicAdd(&hist[(uint)emb[e].y & 511u], 1);
    __syncthreads();

    int v = (t < 512) ? hist[t] : 0;
    for (int off = 1; off < 512; off <<= 1) {
        int x = (t < 512 && t >= off) ? hist[t - off] : 0;
        __syncthreads();
        if (t < 512) hist[t] += x;
        __syncthreads();
    }
    if (t < 512) {
        int excl = hist[t] - v;
        cursor[t] = beg + excl;
        if (t < nnodes) rowptr[nbase + t] = beg + excl;
    }
    __syncthreads();

    for (int e = beg + t; e < end; e += 1024) {
        int2 m = emb[e];
        int p = atomicAdd(&cursor[(uint)m.y & 511u], 1);
        em[p] = make_int2(m.x, (int)((uint)m.y & 0xffff0000u));
    }
}

// ---------------------------------------------------------------------------
// Aggregation: one wave per node, 4 x 16-lane groups; group g handles edge
// e+g, slot covers 16B (F=128) / 8B (F=64) of the row. 2-deep unroll.
// ---------------------------------------------------------------------------

template <int F>
__global__ __launch_bounds__(256) void agg_kernel(const ushort* __restrict__ h,
                                                  const int* __restrict__ rowptr,
                                                  const int2* __restrict__ em,
                                                  ushort* __restrict__ agg) {
    int node = blockIdx.x * 4 + (threadIdx.x >> 6);
    int lane = threadIdx.x & 63;
    int g  = lane >> 4;
    int sl = lane & 15;
    int beg = rowptr[node], end = rowptr[node + 1];
    int e = beg;

    if (F == 128) {
        float acc[8] = {};
        for (; e + 8 <= end; e += 8) {
            int2 mA = em[e + g];
            int2 mB = em[e + 4 + g];
            uint4 vA = *(const uint4*)(h + (size_t)mA.x * 128 + sl * 8);
            uint4 vB = *(const uint4*)(h + (size_t)mB.x * 128 + sl * 8);
            float wA = __int_as_float(mA.y), wB = __int_as_float(mB.y);
            acc[0] = fmaf(b2f_lo(vA.x), wA, acc[0]);
            acc[1] = fmaf(b2f_hi(vA.x), wA, acc[1]);
            acc[2] = fmaf(b2f_lo(vA.y), wA, acc[2]);
            acc[3] = fmaf(b2f_hi(vA.y), wA, acc[3]);
            acc[4] = fmaf(b2f_lo(vA.z), wA, acc[4]);
            acc[5] = fmaf(b2f_hi(vA.z), wA, acc[5]);
            acc[6] = fmaf(b2f_lo(vA.w), wA, acc[6]);
            acc[7] = fmaf(b2f_hi(vA.w), wA, acc[7]);
            acc[0] = fmaf(b2f_lo(vB.x), wB, acc[0]);
            acc[1] = fmaf(b2f_hi(vB.x), wB, acc[1]);
            acc[2] = fmaf(b2f_lo(vB.y), wB, acc[2]);
            acc[3] = fmaf(b2f_hi(vB.y), wB, acc[3]);
            acc[4] = fmaf(b2f_lo(vB.z), wB, acc[4]);
            acc[5] = fmaf(b2f_hi(vB.z), wB, acc[5]);
            acc[6] = fmaf(b2f_lo(vB.w), wB, acc[6]);
            acc[7] = fmaf(b2f_hi(vB.w), wB, acc[7]);
        }
        for (; e < end; e += 4) {
            int ej = e + g;
            if (ej < end) {
                int2 m = em[ej];
                uint4 v = *(const uint4*)(h + (size_t)m.x * 128 + sl * 8);
                float w = __int_as_float(m.y);
                acc[0] = fmaf(b2f_lo(v.x), w, acc[0]);
                acc[1] = fmaf(b2f_hi(v.x), w, acc[1]);
                acc[2] = fmaf(b2f_lo(v.y), w, acc[2]);
                acc[3] = fmaf(b2f_hi(v.y), w, acc[3]);
                acc[4] = fmaf(b2f_lo(v.z), w, acc[4]);
                acc[5] = fmaf(b2f_hi(v.z), w, acc[5]);
                acc[6] = fmaf(b2f_lo(v.w), w, acc[6]);
                acc[7] = fmaf(b2f_hi(v.w), w, acc[7]);
            }
        }
        #pragma unroll
        for (int f = 0; f < 8; ++f) {
            acc[f] += __shfl_xor(acc[f], 16);
            acc[f] += __shfl_xor(acc[f], 32);
        }
        if (lane < 16) {
            uint4 o;
            o.x = pack2(acc[0], acc[1]);
            o.y = pack2(acc[2], acc[3]);
            o.z = pack2(acc[4], acc[5]);
            o.w = pack2(acc[6], acc[7]);
            *(uint4*)(agg + (size_t)node * 128 + sl * 8) = o;
        }
    } else {
        float acc[4] = {};
        for (; e + 8 <= end; e += 8) {
            int2 mA = em[e + g];
            int2 mB = em[e + 4 + g];
            uint2 vA = *(const uint2*)(h + (size_t)mA.x * 64 + sl * 4);
            uint2 vB = *(const uint2*)(h + (size_t)mB.x * 64 + sl * 4);
            float wA = __int_as_float(mA.y), wB = __int_as_float(mB.y);
            acc[0] = fmaf(b2f_lo(vA.x), wA, acc[0]);
            acc[1] = fmaf(b2f_hi(vA.x), wA, acc[1]);
            acc[2] = fmaf(b2f_lo(vA.y), wA, acc[2]);
            acc[3] = fmaf(b2f_hi(vA.y), wA, acc[3]);
            acc[0] = fmaf(b2f_lo(vB.x), wB, acc[0]);
            acc[1] = fmaf(b2f_hi(vB.x), wB, acc[1]);
            acc[2] = fmaf(b2f_lo(vB.y), wB, acc[2]);
            acc[3] = fmaf(b2f_hi(vB.y), wB, acc[3]);
        }
        for (; e < end; e += 4) {
            int ej = e + g;
            if (ej < end) {
                int2 m = em[ej];
                uint2 v = *(const uint2*)(h + (size_t)m.x * 64 + sl * 4);
                float w = __int_as_float(m.y);
                acc[0] = fmaf(b2f_lo(v.x), w, acc[0]);
                acc[1] = fmaf(b2f_hi(v.x), w, acc[1]);
                acc[2] = fmaf(b2f_lo(v.y), w, acc[2]);
                acc[3] = fmaf(b2f_hi(v.y), w, acc[3]);
            }
        }
        #pragma unroll
        for (int f = 0; f < 4; ++f) {
            acc[f] += __shfl_xor(acc[f], 16);
            acc[f] += __shfl_xor(acc[f], 32);
        }
        if (lane < 16) {
            uint2 o;
            o.x = pack2(acc[0], acc[1]);
            o.y = pack2(acc[2], acc[3]);
            *(uint2*)(agg + (size_t)node * 64 + sl * 4) = o;
        }
    }
}

// ---------------------------------------------------------------------------
// MFMA GEMM + bias + BN + ReLU. bf16 in, fp32 accum, bf16 out. K = 2F.
// R9 structure (measured best: 454 us total): K-split W half-panel in LDS
// (35 KB -> 4 blocks/CU), A streamed with 1-deep register prefetch per half.
// NOTE: R10 (all-A-upfront register file) and R11 (fused pooling epilogue)
// both regressed by breaking occupancy -- do not re-complicate this kernel.
// ---------------------------------------------------------------------------

template <int F>
__global__ __launch_bounds__(256, 4) void gemm_mfma(const ushort* __restrict__ A0,
                                                    const ushort* __restrict__ A1,
                                                    const ushort* __restrict__ Wb,
                                                    const float* __restrict__ bias,
                                                    const float* __restrict__ bng,
                                                    const float* __restrict__ bnb,
                                                    const float* __restrict__ bnm,
                                                    const float* __restrict__ bnv,
                                                    ushort* __restrict__ out) {
    constexpr int K = 2 * F;
    constexpr int LDW = F + 8;
    __shared__ ushort Wl[128 * LDW];

    int t = threadIdx.x;
    int wave = t >> 6, lane = t & 63;
    int m = lane & 15, quad = lane >> 4;
    int r0 = blockIdx.x * 128 + wave * 32 + m;
    int r1 = r0 + 16;

    f32x4 acc0[8], acc1[8];
    #pragma unroll
    for (int i = 0; i < 8; ++i) { acc0[i] = (f32x4)(0.f); acc1[i] = (f32x4)(0.f); }

    #pragma unroll
    for (int half = 0; half < 2; ++half) {
        const ushort* A = half ? A1 : A0;
        for (int idx = t; idx < 128 * (F / 8); idx += 256) {
            int c  = idx / (F / 8);
            int k8 = (idx % (F / 8)) * 8;
            *(short8*)&Wl[c * LDW + k8] = *(const short8*)&Wb[c * K + half * F + k8];
        }
        __syncthreads();

        auto loadA = [&](int row, int k0) -> short8 {
            short8 v = {};
            if (row < N_NODES) v = *(const short8*)(A + (size_t)row * F + k0);
            return v;
        };

        short8 a0 = loadA(r0, quad * 8);
        short8 a1 = loadA(r1, quad * 8);
        for (int kc = 0; kc < F; kc += 32) {
            int k0 = kc + quad * 8;
            short8 na0 = {}, na1 = {};
            if (kc + 32 < F) {
                na0 = loadA(r0, k0 + 32);
                na1 = loadA(r1, k0 + 32);
            }
            #pragma unroll
            for (int ct = 0; ct < 8; ++ct) {
                short8 b = *(const short8*)&Wl[(ct * 16 + m) * LDW + k0];
                acc0[ct] = __builtin_amdgcn_mfma_f32_16x16x32_bf16(a0, b, acc0[ct], 0, 0, 0);
                acc1[ct] = __builtin_amdgcn_mfma_f32_16x16x32_bf16(a1, b, acc1[ct], 0, 0, 0);
            }
            a0 = na0; a1 = na1;
        }
        __syncthreads();
    }

    int rb0 = blockIdx.x * 128 + wave * 32 + quad * 4;
    #pragma unroll
    for (int ct = 0; ct < 8; ++ct) {
        int c = ct * 16 + m;
        float sc = bng[c] * rsqrtf(bnv[c] + EPS);
        float sh = bnb[c] - bnm[c] * sc;
        float bi = bias[c];
        #pragma unroll
        for (int reg = 0; reg < 4; ++reg) {
            int r = rb0 + reg;
            if (r < N_NODES) {
                float v = fmaxf(fmaf(acc0[ct][reg] + bi, sc, sh), 0.f);
                out[(size_t)r * 128 + c] = f2b(v);
            }
            int r2 = rb0 + 16 + reg;
            if (r2 < N_NODES) {
                float v = fmaxf(fmaf(acc1[ct][reg] + bi, sc, sh), 0.f);
                out[(size_t)r2 * 128 + c] = f2b(v);
            }
        }
    }
}

// ---------------------------------------------------------------------------
// Pooling: sorted batch -> run-length accumulate; uint loads (2 feats/lane)
// ---------------------------------------------------------------------------

#define POOL_NODES 64
__global__ __launch_bounds__(256) void pool_kernel(const ushort* __restrict__ h,
                                                   const int* __restrict__ batch,
                                                   float* __restrict__ pooled) {
    __shared__ int gb[POOL_NODES];
    int b = blockIdx.x, t = threadIdx.x;
    int n0 = b * POOL_NODES;
    if (t < POOL_NODES) {
        int n = n0 + t;
        gb[t] = (n < N_NODES) ? batch[n] : -1;
    }
    __syncthreads();
    int f2 = t & 63;
    int q  = t >> 6;
    const uint* hp = (const uint*)h;
    float alo = 0.f, ahi = 0.f;
    int gcur = -1;
    for (int i = q; i < POOL_NODES; i += 4) {
        int n = n0 + i;
        if (n >= N_NODES) break;
        int g = gb[i];
        if (g != gcur) {
            if (gcur >= 0) {
                atomicAdd(&pooled[(size_t)gcur * 128 + f2 * 2], alo);
                atomicAdd(&pooled[(size_t)gcur * 128 + f2 * 2 + 1], ahi);
            }
            gcur = g;
            alo = 0.f; ahi = 0.f;
        }
        uint u = hp[(size_t)n * 64 + f2];
        alo += b2f_lo(u);
        ahi += b2f_hi(u);
    }
    if (gcur >= 0) {
        atomicAdd(&pooled[(size_t)gcur * 128 + f2 * 2], alo);
        atomicAdd(&pooled[(size_t)gcur * 128 + f2 * 2 + 1], ahi);
    }
}

// ---------------------------------------------------------------------------
// Head: counts via binary search on sorted batch, one wave per graph
// ---------------------------------------------------------------------------

__global__ __launch_bounds__(64) void head_kernel(const float* __restrict__ pooled,
                                                  const int* __restrict__ batch,
                                                  const float* __restrict__ w1,
                                                  const float* __restrict__ b1,
                                                  const float* __restrict__ w2,
                                                  const float* __restrict__ b2,
                                                  float* __restrict__ out) {
    int g = blockIdx.x;
    int j = threadIdx.x;
    int lo = 0, hi = N_NODES;
    while (lo < hi) { int m = (lo + hi) >> 1; if (batch[m] <  g) lo = m + 1; else hi = m; }
    int start = lo;
    lo = 0; hi = N_NODES;
    while (lo < hi) { int m = (lo + hi) >> 1; if (batch[m] <= g) lo = m + 1; else hi = m; }
    float inv = 1.0f / fmaxf((float)(lo - start), 1.0f);

    float acc = b1[j];
    #pragma unroll 4
    for (int k = 0; k < 128; ++k)
        acc = fmaf(pooled[(size_t)g * 128 + k] * inv, w1[k * 64 + j], acc);
    float prod = fmaxf(acc, 0.f) * w2[j];
    #pragma unroll
    for (int off = 32; off > 0; off >>= 1)
        prod += __shfl_down(prod, off);
    if (j == 0) out[g] = prod + b2[0];
}

// ---------------------------------------------------------------------------

extern "C" void kernel_launch(void* const* d_in, const int* in_sizes, int n_in,
                              void* d_out, int out_size, void* d_ws, size_t ws_size,
                              hipStream_t stream) {
    const float* x     = (const float*)d_in[0];
    const int*   ei    = (const int*)d_in[1];
    const float* ea    = (const float*)d_in[2];
    const int*   batch = (const int*)d_in[3];
    const float* rel_w[3]  = {(const float*)d_in[4],  (const float*)d_in[11], (const float*)d_in[18]};
    const float* rel_b[3]  = {(const float*)d_in[5],  (const float*)d_in[12], (const float*)d_in[19]};
    const float* root_w[3] = {(const float*)d_in[6],  (const float*)d_in[13], (const float*)d_in[20]};
    const float* bn_g[3]   = {(const float*)d_in[7],  (const float*)d_in[14], (const float*)d_in[21]};
    const float* bn_b[3]   = {(const float*)d_in[8],  (const float*)d_in[15], (const float*)d_in[22]};
    const float* bn_m[3]   = {(const float*)d_in[9],  (const float*)d_in[16], (const float*)d_in[23]};
    const float* bn_v[3]   = {(const float*)d_in[10], (const float*)d_in[17], (const float*)d_in[24]};
    const float* head_w1 = (const float*)d_in[25];
    const float* head_b1 = (const float*)d_in[26];
    const float* head_w2 = (const float*)d_in[27];
    const float* head_b2 = (const float*)d_in[28];
    float* out = (float*)d_out;

    // workspace layout (~104 MB)
    char* ws = (char*)d_ws;
    int*    rowptr  = (int*)(ws + 0);             // N_NODES+1 ints
    int*    counts  = (int*)(ws + 401408);        // SCAN_M ints
    int*    partial = (int*)(ws + 503808);        // SCAN_T ints
    int2*   em      = (int2*)(ws + 524288);       // E int2 (src, bf16 w bits)
    ushort* xb      = (ushort*)(ws + 13631488);   // N*64 bf16
    ushort* h_a     = (ushort*)(ws + 26431488);   // N*128 bf16
    ushort* h_b     = (ushort*)(ws + 52031488);   // N*128 bf16
    ushort* aggb    = (ushort*)(ws + 77631488);   // N*128 bf16 (layer0 uses N*64)
    float*  pooled  = (float*)(ws + 103231488);   // 1024*128 fp32
    ushort* wb      = (ushort*)(ws + 103755776);  // 81920 bf16 (3 W panels)
    // sort scratch aliases aggb region (dead until first agg)
    int2*   emb = (int2*)(ws + 77631488);         // E int2 packed

    ushort* wb0 = wb;            // 128*128
    ushort* wb1 = wb + 16384;    // 128*256
    ushort* wb2 = wb + 49152;    // 128*256

    const int PREP_BLOCKS = NBLK_A + (PREP_TOT + 255) / 256;
    prep_count_kernel<<<PREP_BLOCKS, 256, 0, stream>>>(
        x, (uint*)xb, rel_w[0], root_w[0], rel_w[1], root_w[1], rel_w[2], root_w[2],
        (uint*)wb0, (uint*)wb1, (uint*)wb2, pooled, ei, counts);

    sc_reduce_kernel<<<SCAN_T, 1024, 0, stream>>>(counts, partial);
    sc_apply_kernel<<<SCAN_T, 1024, 0, stream>>>(counts, partial, rowptr);
    bin_scatter_kernel<<<NBLK_A, 256, 0, stream>>>(ei, ea, counts, emb);
    bucket_build_kernel<<<NBUCK, 1024, 0, stream>>>(counts, emb, rowptr, em);

    const int AGG_BLOCKS  = N_NODES / 4;
    const int GEMM_BLOCKS = (N_NODES + 127) / 128;

    agg_kernel<64><<<AGG_BLOCKS, 256, 0, stream>>>(xb, rowptr, em, aggb);
    gemm_mfma<64><<<GEMM_BLOCKS, 256, 0, stream>>>(aggb, xb, wb0, rel_b[0],
                                                   bn_g[0], bn_b[0], bn_m[0], bn_v[0], h_a);
    agg_kernel<128><<<AGG_BLOCKS, 256, 0, stream>>>(h_a, rowptr, em, aggb);
    gemm_mfma<128><<<GEMM_BLOCKS, 256, 0, stream>>>(aggb, h_a, wb1, rel_b[1],
                                                    bn_g[1], bn_b[1], bn_m[1], bn_v[1], h_b);
    agg_kernel<128><<<AGG_BLOCKS, 256, 0, stream>>>(h_b, rowptr, em, aggb);
    gemm_mfma<128><<<GEMM_BLOCKS, 256, 0, stream>>>(aggb, h_b, wb2, rel_b[2],
                                                    bn_g[2], bn_b[2], bn_m[2], bn_v[2], h_a);

    pool_kernel<<<(N_NODES + POOL_NODES - 1) / POOL_NODES, 256, 0, stream>>>(h_a, batch, pooled);
    head_kernel<<<N_GRAPHS, 64, 0, stream>>>(pooled, batch, head_w1, head_b1, head_w2, head_b2, out);
}

// Round 13
// 438.020 us; speedup vs baseline: 1.1782x; 1.0500x over previous
//
#include <hip/hip_runtime.h>

#define N_NODES 100000
#define N_EDGES 1600000
#define F_IN 64
#define HIDDEN 128
#define N_GRAPHS 1024
#define EPS 1e-5f

typedef short short8 __attribute__((ext_vector_type(8)));
typedef float f32x4 __attribute__((ext_vector_type(4)));
typedef unsigned int uint;
typedef unsigned short ushort;

// fp32 -> bf16 round-to-nearest-even (finite values only)
__device__ __forceinline__ ushort f2b(float f) {
    uint x = __float_as_uint(f);
    return (ushort)((x + 0x7fffu + ((x >> 16) & 1u)) >> 16);
}
__device__ __forceinline__ uint pack2(float a, float b) {
    return (uint)f2b(a) | ((uint)f2b(b) << 16);
}
__device__ __forceinline__ float b2f_lo(uint u) { return __uint_as_float(u << 16); }
__device__ __forceinline__ float b2f_hi(uint u) { return __uint_as_float(u & 0xffff0000u); }

// two-level counting sort parameters
// NBLK_A=512 (was 128): bin_count/bin_scatter were 2 waves/CU -> now 8/CU.
#define NBLK_A 512
#define CHUNK ((N_EDGES + NBLK_A - 1) / NBLK_A)        // 3125
#define BUCK_SHIFT 9                                    // 512-node windows
#define NBUCK ((N_NODES + 511) / 512)                   // 196
#define SCAN_M (NBUCK * NBLK_A)                         // 100352
#define SCAN_T ((SCAN_M + 1023) / 1024)                 // 98 tiles

// ---------------------------------------------------------------------------
// Fused prep (x->bf16, W->bf16 [c][k], pooled zero) + bin_count.
// ---------------------------------------------------------------------------

#define PREP_X   (N_NODES * 32)       // uints of xb
#define PREP_W0  8192                 // uints of wb0 (128*128/2)
#define PREP_W1  16384                // uints of wb1 (128*256/2)
#define PREP_W2  16384
#define PREP_PZ  (N_GRAPHS * HIDDEN)  // floats of pooled
#define PREP_TOT (PREP_X + PREP_W0 + PREP_W1 + PREP_W2 + PREP_PZ)

__device__ __forceinline__ void cvt_w_elem(const float* W0, const float* W1, int F,
                                           int idx, uint* out) {
    int K = 2 * F;
    int c  = idx / (K / 2);
    int k2 = (idx % (K / 2)) * 2;
    float f0 = (k2 < F) ? W0[k2 * 128 + c] : W1[(k2 - F) * 128 + c];
    float f1 = (k2 + 1 < F) ? W0[(k2 + 1) * 128 + c] : W1[(k2 + 1 - F) * 128 + c];
    out[idx] = pack2(f0, f1);
}

__global__ __launch_bounds__(256) void prep_count_kernel(
        const float* __restrict__ x, uint* __restrict__ xb,
        const float* __restrict__ rw0, const float* __restrict__ ow0,
        const float* __restrict__ rw1, const float* __restrict__ ow1,
        const float* __restrict__ rw2, const float* __restrict__ ow2,
        uint* __restrict__ wb0, uint* __restrict__ wb1,
        uint* __restrict__ wb2, float* __restrict__ pooled,
        const int* __restrict__ ei, int* __restrict__ counts) {
    __shared__ int cnt[NBUCK];
    int t = threadIdx.x;
    if (blockIdx.x < NBLK_A) {
        int blk = blockIdx.x;
        for (int i = t; i < NBUCK; i += 256) cnt[i] = 0;
        __syncthreads();
        int e0 = blk * CHUNK, e1 = min(e0 + CHUNK, N_EDGES);
        for (int e = e0 + t; e < e1; e += 256)
            atomicAdd(&cnt[ei[N_EDGES + e] >> BUCK_SHIFT], 1);
        __syncthreads();
        for (int i = t; i < NBUCK; i += 256) counts[i * NBLK_A + blk] = cnt[i];
        return;
    }
    int i = (blockIdx.x - NBLK_A) * 256 + t;
    if (i < PREP_X) {
        float2 v = ((const float2*)x)[i];
        xb[i] = pack2(v.x, v.y);
        return;
    }
    i -= PREP_X;
    if (i < PREP_W0) { cvt_w_elem(rw0, ow0, 64, i, wb0); return; }
    i -= PREP_W0;
    if (i < PREP_W1) { cvt_w_elem(rw1, ow1, 128, i, wb1); return; }
    i -= PREP_W1;
    if (i < PREP_W2) { cvt_w_elem(rw2, ow2, 128, i, wb2); return; }
    i -= PREP_W2;
    if (i < PREP_PZ) pooled[i] = 0.f;
}

// ---------------------------------------------------------------------------
// Hierarchical exclusive scan of counts[SCAN_M]
// ---------------------------------------------------------------------------

__global__ __launch_bounds__(1024) void sc_reduce_kernel(const int* __restrict__ counts,
                                                         int* __restrict__ partial) {
    __shared__ int lds[16];
    int b = blockIdx.x, t = threadIdx.x;
    int i = b * 1024 + t;
    int v = (i < SCAN_M) ? counts[i] : 0;
    #pragma unroll
    for (int off = 32; off > 0; off >>= 1) v += __shfl_down(v, off);
    if ((t & 63) == 0) lds[t >> 6] = v;
    __syncthreads();
    if (t == 0) {
        int s = 0;
        #pragma unroll
        for (int j = 0; j < 16; ++j) s += lds[j];
        partial[b] = s;
    }
}

// apply: block offset via wave-parallel load of partials (2/lane) + shfl reduce
__global__ __launch_bounds__(1024) void sc_apply_kernel(int* __restrict__ counts,
                                                        const int* __restrict__ partial,
                                                        int* __restrict__ rowptr) {
    __shared__ int lds[1024];
    __shared__ int sbase;
    int b = blockIdx.x, t = threadIdx.x;
    if (t < 64) {
        int v = 0;
        if (t < b) v += partial[t];                     // SCAN_T = 98 <= 128
        if (t + 64 < b) v += partial[t + 64];
        #pragma unroll
        for (int off = 32; off > 0; off >>= 1) v += __shfl_down(v, off);
        if (t == 0) {
            sbase = v;
            if (b == 0) rowptr[N_NODES] = N_EDGES;
        }
    }
    int i = b * 1024 + t;
    int v = (i < SCAN_M) ? counts[i] : 0;
    lds[t] = v;
    __syncthreads();
    for (int off = 1; off < 1024; off <<= 1) {
        int x = (t >= off) ? lds[t - off] : 0;
        __syncthreads();
        lds[t] += x;
        __syncthreads();
    }
    if (i < SCAN_M) counts[i] = lds[t] - v + sbase;
}

// scatter edges into coarse-bucket order; payload packed to one int2:
//   x = src, y = (bf16(w) << 16) | (dst & 511)
__global__ __launch_bounds__(256) void bin_scatter_kernel(const int* __restrict__ ei,
                                                          const float* __restrict__ ea,
                                                          const int* __restrict__ counts,
                                                          int2* __restrict__ emb) {
    __shared__ int cur[NBUCK];
    int blk = blockIdx.x, t = threadIdx.x;
    for (int i = t; i < NBUCK; i += 256) cur[i] = counts[i * NBLK_A + blk];
    __syncthreads();
    int e0 = blk * CHUNK, e1 = min(e0 + CHUNK, N_EDGES);
    for (int e = e0 + t; e < e1; e += 256) {
        int s = ei[e], d = ei[N_EDGES + e];
        uint y = ((uint)f2b(ea[e]) << 16) | (uint)(d & 511);
        int p = atomicAdd(&cur[d >> BUCK_SHIFT], 1);
        emb[p] = make_int2(s, (int)y);
    }
}

// per-bucket exact sort + rowptr; final em: x = src, y = float bits of bf16 w
__global__ __launch_bounds__(1024) void bucket_build_kernel(const int* __restrict__ counts,
                                                            const int2* __restrict__ emb,
                                                            int* __restrict__ rowptr,
                                                            int2* __restrict__ em) {
    __shared__ int hist[512];
    __shared__ int cursor[512];
    int b = blockIdx.x, t = threadIdx.x;
    int beg = counts[b * NBLK_A];
    int end = (b + 1 < NBUCK) ? counts[(b + 1) * NBLK_A] : N_EDGES;
    int nbase = b << BUCK_SHIFT;
    int nnodes = min(512, N_NODES - nbase);

    if (t < 512) hist[t] = 0;
    __syncthreads();
    for (int e = beg + t; e < end; e += 1024)
        atomicAdd(&hist[(uint)emb[e].y & 511u], 1);
    __syncthreads();

    int v = (t < 512) ? hist[t] : 0;
    for (int off = 1; off < 512; off <<= 1) {
        int x = (t < 512 && t >= off) ? hist[t - off] : 0;
        __syncthreads();
        if (t < 512) hist[t] += x;
        __syncthreads();
    }
    if (t < 512) {
        int excl = hist[t] - v;
        cursor[t] = beg + excl;
        if (t < nnodes) rowptr[nbase + t] = beg + excl;
    }
    __syncthreads();

    for (int e = beg + t; e < end; e += 1024) {
        int2 m = emb[e];
        int p = atomicAdd(&cursor[(uint)m.y & 511u], 1);
        em[p] = make_int2(m.x, (int)((uint)m.y & 0xffff0000u));
    }
}

// ---------------------------------------------------------------------------
// Aggregation: one wave per node, 4 x 16-lane groups; group g handles edge
// e+g, slot covers 16B (F=128) / 8B (F=64) of the row. 2-deep unroll.
// ---------------------------------------------------------------------------

template <int F>
__global__ __launch_bounds__(256) void agg_kernel(const ushort* __restrict__ h,
                                                  const int* __restrict__ rowptr,
                                                  const int2* __restrict__ em,
                                                  ushort* __restrict__ agg) {
    int node = blockIdx.x * 4 + (threadIdx.x >> 6);
    int lane = threadIdx.x & 63;
    int g  = lane >> 4;
    int sl = lane & 15;
    int beg = rowptr[node], end = rowptr[node + 1];
    int e = beg;

    if (F == 128) {
        float acc[8] = {};
        for (; e + 8 <= end; e += 8) {
            int2 mA = em[e + g];
            int2 mB = em[e + 4 + g];
            uint4 vA = *(const uint4*)(h + (size_t)mA.x * 128 + sl * 8);
            uint4 vB = *(const uint4*)(h + (size_t)mB.x * 128 + sl * 8);
            float wA = __int_as_float(mA.y), wB = __int_as_float(mB.y);
            acc[0] = fmaf(b2f_lo(vA.x), wA, acc[0]);
            acc[1] = fmaf(b2f_hi(vA.x), wA, acc[1]);
            acc[2] = fmaf(b2f_lo(vA.y), wA, acc[2]);
            acc[3] = fmaf(b2f_hi(vA.y), wA, acc[3]);
            acc[4] = fmaf(b2f_lo(vA.z), wA, acc[4]);
            acc[5] = fmaf(b2f_hi(vA.z), wA, acc[5]);
            acc[6] = fmaf(b2f_lo(vA.w), wA, acc[6]);
            acc[7] = fmaf(b2f_hi(vA.w), wA, acc[7]);
            acc[0] = fmaf(b2f_lo(vB.x), wB, acc[0]);
            acc[1] = fmaf(b2f_hi(vB.x), wB, acc[1]);
            acc[2] = fmaf(b2f_lo(vB.y), wB, acc[2]);
            acc[3] = fmaf(b2f_hi(vB.y), wB, acc[3]);
            acc[4] = fmaf(b2f_lo(vB.z), wB, acc[4]);
            acc[5] = fmaf(b2f_hi(vB.z), wB, acc[5]);
            acc[6] = fmaf(b2f_lo(vB.w), wB, acc[6]);
            acc[7] = fmaf(b2f_hi(vB.w), wB, acc[7]);
        }
        for (; e < end; e += 4) {
            int ej = e + g;
            if (ej < end) {
                int2 m = em[ej];
                uint4 v = *(const uint4*)(h + (size_t)m.x * 128 + sl * 8);
                float w = __int_as_float(m.y);
                acc[0] = fmaf(b2f_lo(v.x), w, acc[0]);
                acc[1] = fmaf(b2f_hi(v.x), w, acc[1]);
                acc[2] = fmaf(b2f_lo(v.y), w, acc[2]);
                acc[3] = fmaf(b2f_hi(v.y), w, acc[3]);
                acc[4] = fmaf(b2f_lo(v.z), w, acc[4]);
                acc[5] = fmaf(b2f_hi(v.z), w, acc[5]);
                acc[6] = fmaf(b2f_lo(v.w), w, acc[6]);
                acc[7] = fmaf(b2f_hi(v.w), w, acc[7]);
            }
        }
        #pragma unroll
        for (int f = 0; f < 8; ++f) {
            acc[f] += __shfl_xor(acc[f], 16);
            acc[f] += __shfl_xor(acc[f], 32);
        }
        if (lane < 16) {
            uint4 o;
            o.x = pack2(acc[0], acc[1]);
            o.y = pack2(acc[2], acc[3]);
            o.z = pack2(acc[4], acc[5]);
            o.w = pack2(acc[6], acc[7]);
            *(uint4*)(agg + (size_t)node * 128 + sl * 8) = o;
        }
    } else {
        float acc[4] = {};
        for (; e + 8 <= end; e += 8) {
            int2 mA = em[e + g];
            int2 mB = em[e + 4 + g];
            uint2 vA = *(const uint2*)(h + (size_t)mA.x * 64 + sl * 4);
            uint2 vB = *(const uint2*)(h + (size_t)mB.x * 64 + sl * 4);
            float wA = __int_as_float(mA.y), wB = __int_as_float(mB.y);
            acc[0] = fmaf(b2f_lo(vA.x), wA, acc[0]);
            acc[1] = fmaf(b2f_hi(vA.x), wA, acc[1]);
            acc[2] = fmaf(b2f_lo(vA.y), wA, acc[2]);
            acc[3] = fmaf(b2f_hi(vA.y), wA, acc[3]);
            acc[0] = fmaf(b2f_lo(vB.x), wB, acc[0]);
            acc[1] = fmaf(b2f_hi(vB.x), wB, acc[1]);
            acc[2] = fmaf(b2f_lo(vB.y), wB, acc[2]);
            acc[3] = fmaf(b2f_hi(vB.y), wB, acc[3]);
        }
        for (; e < end; e += 4) {
            int ej = e + g;
            if (ej < end) {
                int2 m = em[ej];
                uint2 v = *(const uint2*)(h + (size_t)m.x * 64 + sl * 4);
                float w = __int_as_float(m.y);
                acc[0] = fmaf(b2f_lo(v.x), w, acc[0]);
                acc[1] = fmaf(b2f_hi(v.x), w, acc[1]);
                acc[2] = fmaf(b2f_lo(v.y), w, acc[2]);
                acc[3] = fmaf(b2f_hi(v.y), w, acc[3]);
            }
        }
        #pragma unroll
        for (int f = 0; f < 4; ++f) {
            acc[f] += __shfl_xor(acc[f], 16);
            acc[f] += __shfl_xor(acc[f], 32);
        }
        if (lane < 16) {
            uint2 o;
            o.x = pack2(acc[0], acc[1]);
            o.y = pack2(acc[2], acc[3]);
            *(uint2*)(agg + (size_t)node * 64 + sl * 4) = o;
        }
    }
}

// ---------------------------------------------------------------------------
// MFMA GEMM + bias + BN + ReLU. bf16 in, fp32 accum, bf16 out. K = 2F.
// R9 structure (measured best): K-split W half-panel in LDS (35 KB ->
// 4 blocks/CU), A streamed with 1-deep register prefetch per half.
// NOTE: R10 (all-A-upfront register file) and R11 (fused pooling epilogue)
// both regressed by breaking occupancy -- do not re-complicate this kernel.
// ---------------------------------------------------------------------------

template <int F>
__global__ __launch_bounds__(256, 4) void gemm_mfma(const ushort* __restrict__ A0,
                                                    const ushort* __restrict__ A1,
                                                    const ushort* __restrict__ Wb,
                                                    const float* __restrict__ bias,
                                                    const float* __restrict__ bng,
                                                    const float* __restrict__ bnb,
                                                    const float* __restrict__ bnm,
                                                    const float* __restrict__ bnv,
                                                    ushort* __restrict__ out) {
    constexpr int K = 2 * F;
    constexpr int LDW = F + 8;
    __shared__ ushort Wl[128 * LDW];

    int t = threadIdx.x;
    int wave = t >> 6, lane = t & 63;
    int m = lane & 15, quad = lane >> 4;
    int r0 = blockIdx.x * 128 + wave * 32 + m;
    int r1 = r0 + 16;

    f32x4 acc0[8], acc1[8];
    #pragma unroll
    for (int i = 0; i < 8; ++i) { acc0[i] = (f32x4)(0.f); acc1[i] = (f32x4)(0.f); }

    #pragma unroll
    for (int half = 0; half < 2; ++half) {
        const ushort* A = half ? A1 : A0;
        for (int idx = t; idx < 128 * (F / 8); idx += 256) {
            int c  = idx / (F / 8);
            int k8 = (idx % (F / 8)) * 8;
            *(short8*)&Wl[c * LDW + k8] = *(const short8*)&Wb[c * K + half * F + k8];
        }
        __syncthreads();

        auto loadA = [&](int row, int k0) -> short8 {
            short8 v = {};
            if (row < N_NODES) v = *(const short8*)(A + (size_t)row * F + k0);
            return v;
        };

        short8 a0 = loadA(r0, quad * 8);
        short8 a1 = loadA(r1, quad * 8);
        for (int kc = 0; kc < F; kc += 32) {
            int k0 = kc + quad * 8;
            short8 na0 = {}, na1 = {};
            if (kc + 32 < F) {
                na0 = loadA(r0, k0 + 32);
                na1 = loadA(r1, k0 + 32);
            }
            #pragma unroll
            for (int ct = 0; ct < 8; ++ct) {
                short8 b = *(const short8*)&Wl[(ct * 16 + m) * LDW + k0];
                acc0[ct] = __builtin_amdgcn_mfma_f32_16x16x32_bf16(a0, b, acc0[ct], 0, 0, 0);
                acc1[ct] = __builtin_amdgcn_mfma_f32_16x16x32_bf16(a1, b, acc1[ct], 0, 0, 0);
            }
            a0 = na0; a1 = na1;
        }
        __syncthreads();
    }

    int rb0 = blockIdx.x * 128 + wave * 32 + quad * 4;
    #pragma unroll
    for (int ct = 0; ct < 8; ++ct) {
        int c = ct * 16 + m;
        float sc = bng[c] * rsqrtf(bnv[c] + EPS);
        float sh = bnb[c] - bnm[c] * sc;
        float bi = bias[c];
        #pragma unroll
        for (int reg = 0; reg < 4; ++reg) {
            int r = rb0 + reg;
            if (r < N_NODES) {
                float v = fmaxf(fmaf(acc0[ct][reg] + bi, sc, sh), 0.f);
                out[(size_t)r * 128 + c] = f2b(v);
            }
            int r2 = rb0 + 16 + reg;
            if (r2 < N_NODES) {
                float v = fmaxf(fmaf(acc1[ct][reg] + bi, sc, sh), 0.f);
                out[(size_t)r2 * 128 + c] = f2b(v);
            }
        }
    }
}

// ---------------------------------------------------------------------------
// Pooling: sorted batch -> run-length accumulate; uint loads (2 feats/lane)
// ---------------------------------------------------------------------------

#define POOL_NODES 64
__global__ __launch_bounds__(256) void pool_kernel(const ushort* __restrict__ h,
                                                   const int* __restrict__ batch,
                                                   float* __restrict__ pooled) {
    __shared__ int gb[POOL_NODES];
    int b = blockIdx.x, t = threadIdx.x;
    int n0 = b * POOL_NODES;
    if (t < POOL_NODES) {
        int n = n0 + t;
        gb[t] = (n < N_NODES) ? batch[n] : -1;
    }
    __syncthreads();
    int f2 = t & 63;
    int q  = t >> 6;
    const uint* hp = (const uint*)h;
    float alo = 0.f, ahi = 0.f;
    int gcur = -1;
    for (int i = q; i < POOL_NODES; i += 4) {
        int n = n0 + i;
        if (n >= N_NODES) break;
        int g = gb[i];
        if (g != gcur) {
            if (gcur >= 0) {
                atomicAdd(&pooled[(size_t)gcur * 128 + f2 * 2], alo);
                atomicAdd(&pooled[(size_t)gcur * 128 + f2 * 2 + 1], ahi);
            }
            gcur = g;
            alo = 0.f; ahi = 0.f;
        }
        uint u = hp[(size_t)n * 64 + f2];
        alo += b2f_lo(u);
        ahi += b2f_hi(u);
    }
    if (gcur >= 0) {
        atomicAdd(&pooled[(size_t)gcur * 128 + f2 * 2], alo);
        atomicAdd(&pooled[(size_t)gcur * 128 + f2 * 2 + 1], ahi);
    }
}

// ---------------------------------------------------------------------------
// Head: counts via binary search on sorted batch, one wave per graph
// ---------------------------------------------------------------------------

__global__ __launch_bounds__(64) void head_kernel(const float* __restrict__ pooled,
                                                  const int* __restrict__ batch,
                                                  const float* __restrict__ w1,
                                                  const float* __restrict__ b1,
                                                  const float* __restrict__ w2,
                                                  const float* __restrict__ b2,
                                                  float* __restrict__ out) {
    int g = blockIdx.x;
    int j = threadIdx.x;
    int lo = 0, hi = N_NODES;
    while (lo < hi) { int m = (lo + hi) >> 1; if (batch[m] <  g) lo = m + 1; else hi = m; }
    int start = lo;
    lo = 0; hi = N_NODES;
    while (lo < hi) { int m = (lo + hi) >> 1; if (batch[m] <= g) lo = m + 1; else hi = m; }
    float inv = 1.0f / fmaxf((float)(lo - start), 1.0f);

    float acc = b1[j];
    #pragma unroll 4
    for (int k = 0; k < 128; ++k)
        acc = fmaf(pooled[(size_t)g * 128 + k] * inv, w1[k * 64 + j], acc);
    float prod = fmaxf(acc, 0.f) * w2[j];
    #pragma unroll
    for (int off = 32; off > 0; off >>= 1)
        prod += __shfl_down(prod, off);
    if (j == 0) out[g] = prod + b2[0];
}

// ---------------------------------------------------------------------------

extern "C" void kernel_launch(void* const* d_in, const int* in_sizes, int n_in,
                              void* d_out, int out_size, void* d_ws, size_t ws_size,
                              hipStream_t stream) {
    const float* x     = (const float*)d_in[0];
    const int*   ei    = (const int*)d_in[1];
    const float* ea    = (const float*)d_in[2];
    const int*   batch = (const int*)d_in[3];
    const float* rel_w[3]  = {(const float*)d_in[4],  (const float*)d_in[11], (const float*)d_in[18]};
    const float* rel_b[3]  = {(const float*)d_in[5],  (const float*)d_in[12], (const float*)d_in[19]};
    const float* root_w[3] = {(const float*)d_in[6],  (const float*)d_in[13], (const float*)d_in[20]};
    const float* bn_g[3]   = {(const float*)d_in[7],  (const float*)d_in[14], (const float*)d_in[21]};
    const float* bn_b[3]   = {(const float*)d_in[8],  (const float*)d_in[15], (const float*)d_in[22]};
    const float* bn_m[3]   = {(const float*)d_in[9],  (const float*)d_in[16], (const float*)d_in[23]};
    const float* bn_v[3]   = {(const float*)d_in[10], (const float*)d_in[17], (const float*)d_in[24]};
    const float* head_w1 = (const float*)d_in[25];
    const float* head_b1 = (const float*)d_in[26];
    const float* head_w2 = (const float*)d_in[27];
    const float* head_b2 = (const float*)d_in[28];
    float* out = (float*)d_out;

    // workspace layout (~106 MB; counts grew to NBUCK*512 ints)
    char* ws = (char*)d_ws;
    int*    rowptr  = (int*)(ws + 0);              // N_NODES+1 ints (400,404 B)
    int*    counts  = (int*)(ws + 524288);         // SCAN_M ints (401,408 B)
    int*    partial = (int*)(ws + 933888);         // SCAN_T ints
    int2*   em      = (int2*)(ws + 1048576);       // E int2 -> ends 13,848,576
    ushort* xb      = (ushort*)(ws + 14155776);    // N*64 bf16 -> ends 26,955,776
    ushort* h_a     = (ushort*)(ws + 27262976);    // N*128 bf16 -> ends 52,862,976
    ushort* h_b     = (ushort*)(ws + 53215232);    // N*128 bf16 -> ends 78,815,232
    ushort* aggb    = (ushort*)(ws + 79167488);    // N*128 bf16 -> ends 104,767,488
    float*  pooled  = (float*)(ws + 104857600);    // 1024*128 fp32
    ushort* wb      = (ushort*)(ws + 105447424);   // 81920 bf16 (3 W panels)
    // sort scratch aliases aggb region (dead until first agg)
    int2*   emb = (int2*)(ws + 79167488);          // E int2 packed

    ushort* wb0 = wb;            // 128*128
    ushort* wb1 = wb + 16384;    // 128*256
    ushort* wb2 = wb + 49152;    // 128*256

    const int PREP_BLOCKS = NBLK_A + (PREP_TOT + 255) / 256;
    prep_count_kernel<<<PREP_BLOCKS, 256, 0, stream>>>(
        x, (uint*)xb, rel_w[0], root_w[0], rel_w[1], root_w[1], rel_w[2], root_w[2],
        (uint*)wb0, (uint*)wb1, (uint*)wb2, pooled, ei, counts);

    sc_reduce_kernel<<<SCAN_T, 1024, 0, stream>>>(counts, partial);
    sc_apply_kernel<<<SCAN_T, 1024, 0, stream>>>(counts, partial, rowptr);
    bin_scatter_kernel<<<NBLK_A, 256, 0, stream>>>(ei, ea, counts, emb);
    bucket_build_kernel<<<NBUCK, 1024, 0, stream>>>(counts, emb, rowptr, em);

    const int AGG_BLOCKS  = N_NODES / 4;
    const int GEMM_BLOCKS = (N_NODES + 127) / 128;

    agg_kernel<64><<<AGG_BLOCKS, 256, 0, stream>>>(xb, rowptr, em, aggb);
    gemm_mfma<64><<<GEMM_BLOCKS, 256, 0, stream>>>(aggb, xb, wb0, rel_b[0],
                                                   bn_g[0], bn_b[0], bn_m[0], bn_v[0], h_a);
    agg_kernel<128><<<AGG_BLOCKS, 256, 0, stream>>>(h_a, rowptr, em, aggb);
    gemm_mfma<128><<<GEMM_BLOCKS, 256, 0, stream>>>(aggb, h_a, wb1, rel_b[1],
                                                    bn_g[1], bn_b[1], bn_m[1], bn_v[1], h_b);
    agg_kernel<128><<<AGG_BLOCKS, 256, 0, stream>>>(h_b, rowptr, em, aggb);
    gemm_mfma<128><<<GEMM_BLOCKS, 256, 0, stream>>>(aggb, h_b, wb2, rel_b[2],
                                                    bn_g[2], bn_b[2], bn_m[2], bn_v[2], h_a);

    pool_kernel<<<(N_NODES + POOL_NODES - 1) / POOL_NODES, 256, 0, stream>>>(h_a, batch, pooled);
    head_kernel<<<N_GRAPHS, 64, 0, stream>>>(pooled, batch, head_w1, head_b1, head_w2, head_b2, out);
}